// Round 14
// baseline (258.493 us; speedup 1.0000x reference)
//
#include <hip/hip_runtime.h>

#define N_NODES 100000
#define N_EDGES 1600000
#define F_IN    128
#define HC      128     // H * C
#define NGRAPH  64
#define NEG_SLOPE 0.2f

static constexpr int TOT_E = N_EDGES + N_NODES;         // with self loops

// CSR binned build
#define CHUNK  2048
#define NBLK   831            // ceil(TOT_E / CHUNK)
#define NBUCK  196            // ceil(N_NODES / 512), bucket = dst >> 9

#define GEMM_B 1563           // ceil(N_NODES / 64)
#define CNT_B  391            // ceil(N_NODES / 256)

typedef __bf16 bf16x8 __attribute__((ext_vector_type(8)));
typedef float  f32x4  __attribute__((ext_vector_type(4)));
typedef float  f32x2  __attribute__((ext_vector_type(2)));

__device__ __forceinline__ unsigned short f2bf_rne(float f) {
    unsigned u = __float_as_uint(f);
    u += 0x7fffu + ((u >> 16) & 1u);
    return (unsigned short)(u >> 16);
}
__device__ __forceinline__ float bf2f(unsigned b) {        // low 16 bits used
    return __uint_as_float(b << 16);
}
__device__ __forceinline__ unsigned char f2fp8(float f) {  // OCP e4m3, HW RNE
    return (unsigned char)(__builtin_amdgcn_cvt_pk_fp8_f32(f, f, 0, 0) & 0xff);
}

// ---------------- device bodies ----------------

// binned partition: edges -> block-local bucket-grouped packed pairs. word = (src<<9)|(dst&511)
__device__ __forceinline__ void binpart_body(int blk, int t,
                                             const int* __restrict__ ei,
                                             unsigned* __restrict__ pairs,
                                             int* __restrict__ seg_start,
                                             int* __restrict__ seg_cnt,
                                             int* cnt, int* wtot) {
    int lane = t & 63, w = t >> 6;
    long base = (long)blk * CHUNK;

    cnt[t] = 0;
    __syncthreads();

    for (int j = t; j < CHUNK; j += 256) {
        long i = base + j;
        int d = -1;
        if (i < N_EDGES)    d = ei[N_EDGES + i];
        else if (i < TOT_E) d = (int)(i - N_EDGES);
        if (d >= 0) atomicAdd(&cnt[d >> 9], 1);
    }
    __syncthreads();

    int c = cnt[t];
    int x = c;
#pragma unroll
    for (int off = 1; off < 64; off <<= 1) {
        int v = __shfl_up(x, off);
        if (lane >= off) x += v;
    }
    if (lane == 63) wtot[w] = x;
    __syncthreads();
    int add = 0;
#pragma unroll
    for (int k = 0; k < 3; ++k) if (k < w) add += wtot[k];
    x += add;
    int st = x - c;
    if (t < NBUCK) {
        seg_start[(size_t)blk * NBUCK + t] = st;
        seg_cnt[(size_t)blk * NBUCK + t]   = c;
    }
    __syncthreads();
    cnt[t] = st;
    __syncthreads();

    for (int j = t; j < CHUNK; j += 256) {
        long i = base + j;
        int s = -1, d = -1;
        if (i < N_EDGES)    { s = ei[i]; d = ei[N_EDGES + i]; }
        else if (i < TOT_E) { s = (int)(i - N_EDGES); d = s; }
        if (d >= 0) {
            int pos = atomicAdd(&cnt[d >> 9], 1);
            pairs[base + pos] = ((unsigned)s << 9) | ((unsigned)d & 511u);
        }
    }
}

// GEMM tile + fused alpha epilogue. H stored fp8 e4m3 (gather table); alpha from fp32 acc.
template<bool BF16IN>
__device__ __forceinline__ void gemm_body(int gbid, int t,
                                          const void* __restrict__ Xv,
                                          const unsigned short* __restrict__ Wt,
                                          unsigned char* __restrict__ Hout,
                                          const float* __restrict__ a_src,
                                          const float* __restrict__ a_dst,
                                          float* __restrict__ asrc,
                                          float* __restrict__ adst,
                                          unsigned short* A_lds) {
    int lane = t & 63, wave = t >> 6;
    int wc = wave & 1, wr = wave >> 1;
    int base = gbid * 64;

    bf16x8 Bf[4][4];
    {
        int colb = wc * 64 + (lane & 15);
        int kbb  = lane >> 4;
#pragma unroll
        for (int ct = 0; ct < 4; ++ct)
#pragma unroll
            for (int ks = 0; ks < 4; ++ks) {
                int kb = kbb + 4 * ks;
                Bf[ct][ks] = *(const bf16x8*)&Wt[(size_t)kb * (HC * 8) + (colb + ct * 16) * 8];
            }
    }

#pragma unroll
    for (int it = 0; it < 8; ++it) {
        int i = t + it * 256;
        int row = i >> 5, c4 = i & 31, k0 = c4 * 4;
        uint2 pk; pk.x = 0; pk.y = 0;
        if (base + row < N_NODES) {
            if (BF16IN) {
                pk = ((const uint2*)Xv)[(size_t)(base + row) * 32 + c4];
            } else {
                float4 v = ((const float4*)Xv)[(size_t)(base + row) * 32 + c4];
                pk.x = (unsigned)f2bf_rne(v.x) | ((unsigned)f2bf_rne(v.y) << 16);
                pk.y = (unsigned)f2bf_rne(v.z) | ((unsigned)f2bf_rne(v.w) << 16);
            }
        }
        int byte = row * 256 + (((k0 >> 3) ^ (row & 7)) << 4) + (k0 & 4) * 2;
        *(uint2*)((char*)A_lds + byte) = pk;
    }
    __syncthreads();

    f32x4 acc[2][4] = {};
#pragma unroll
    for (int ks = 0; ks < 4; ++ks) {
        bf16x8 Af[2];
#pragma unroll
        for (int r = 0; r < 2; ++r) {
            int row = wr * 32 + r * 16 + (lane & 15);
            int kb  = ks * 4 + (lane >> 4);
            int byte = row * 256 + ((kb ^ (row & 7)) << 4);
            Af[r] = *(const bf16x8*)((const char*)A_lds + byte);
        }
#pragma unroll
        for (int ct = 0; ct < 4; ++ct) {
            acc[0][ct] = __builtin_amdgcn_mfma_f32_16x16x32_bf16(Af[0], Bf[ct][ks], acc[0][ct], 0, 0, 0);
            acc[1][ct] = __builtin_amdgcn_mfma_f32_16x16x32_bf16(Af[1], Bf[ct][ks], acc[1][ct], 0, 0, 0);
        }
    }

    // H store (fp8 e4m3)
#pragma unroll
    for (int r = 0; r < 2; ++r) {
        int row0 = base + wr * 32 + r * 16 + (lane >> 4) * 4;
#pragma unroll
        for (int reg = 0; reg < 4; ++reg) {
            int row = row0 + reg;
            if (row < N_NODES) {
#pragma unroll
                for (int ct = 0; ct < 4; ++ct) {
                    int col = wc * 64 + ct * 16 + (lane & 15);
                    Hout[(size_t)row * HC + col] = f2fp8(acc[r][ct][reg]);
                }
            }
        }
    }

    // fused alpha (exact fp32 acc)
    float as_c[4], ad_c[4];
#pragma unroll
    for (int ct = 0; ct < 4; ++ct) {
        int ch = wc * 64 + ct * 16 + (lane & 15);
        as_c[ct] = a_src[ch];
        ad_c[ct] = a_dst[ch];
    }
#pragma unroll
    for (int r = 0; r < 2; ++r) {
#pragma unroll
        for (int reg = 0; reg < 4; ++reg) {
            float ps = acc[r][0][reg] * as_c[0] + acc[r][1][reg] * as_c[1]
                     + acc[r][2][reg] * as_c[2] + acc[r][3][reg] * as_c[3];
            float pd = acc[r][0][reg] * ad_c[0] + acc[r][1][reg] * ad_c[1]
                     + acc[r][2][reg] * ad_c[2] + acc[r][3][reg] * ad_c[3];
#pragma unroll
            for (int off = 1; off < 16; off <<= 1) {
                ps += __shfl_xor(ps, off);
                pd += __shfl_xor(pd, off);
            }
            if ((lane & 15) == 0) {
                int row = base + wr * 32 + r * 16 + (lane >> 4) * 4 + reg;
                if (row < N_NODES) {
                    asrc[(size_t)row * 2 + wc] = ps;
                    adst[(size_t)row * 2 + wc] = pd;
                }
            }
        }
    }
}

// ---------------- fused main: gemm1 ⊗ binpart ⊗ counts ----------------

__global__ __launch_bounds__(256) void fused_main(const float* __restrict__ x,
                                                  const unsigned short* __restrict__ wt1,
                                                  unsigned char* __restrict__ hA,
                                                  const float* __restrict__ a1s,
                                                  const float* __restrict__ a1d,
                                                  float* __restrict__ asrc,
                                                  float* __restrict__ adst,
                                                  const int* __restrict__ ei,
                                                  unsigned* __restrict__ pairs,
                                                  int* __restrict__ seg_start,
                                                  int* __restrict__ seg_cnt,
                                                  const int* __restrict__ batch,
                                                  int* __restrict__ counts) {
    __shared__ unsigned short A_lds[64 * F_IN];   // 16 KB (gemm branch)
    __shared__ int cnt[256];                      // binpart branch
    __shared__ int wtot[4];
    __shared__ int loc[NGRAPH];                   // counts branch
    int bid = blockIdx.x, t = threadIdx.x;

    if (bid < 2 * NBLK) {
        if (bid & 1) binpart_body(bid >> 1, t, ei, pairs, seg_start, seg_cnt, cnt, wtot);
        else         gemm_body<false>(bid >> 1, t, x, wt1, hA, a1s, a1d, asrc, adst, A_lds);
    } else if (bid < NBLK + GEMM_B) {
        gemm_body<false>(bid - NBLK, t, x, wt1, hA, a1s, a1d, asrc, adst, A_lds);
    } else {
        int cb = bid - (NBLK + GEMM_B);
        if (t < NGRAPH) loc[t] = 0;
        __syncthreads();
        int i = cb * 256 + t;
        if (i < N_NODES) atomicAdd(&loc[batch[i]], 1);
        __syncthreads();
        if (t < NGRAPH && loc[t]) atomicAdd(&counts[t], loc[t]);
    }
}

// ---------------- standalone gemm (layer 2: bf16 in, fp8 out) ----------------

__global__ __launch_bounds__(256) void gemm2_kernel(const unsigned short* __restrict__ Xv,
                                                    const unsigned short* __restrict__ Wt,
                                                    unsigned char* __restrict__ Hout,
                                                    const float* __restrict__ a_src,
                                                    const float* __restrict__ a_dst,
                                                    float* __restrict__ asrc,
                                                    float* __restrict__ adst) {
    __shared__ unsigned short A_lds[64 * F_IN];
    gemm_body<true>(blockIdx.x, threadIdx.x, Xv, Wt, Hout, a_src, a_dst, asrc, adst, A_lds);
}

// ---------------- per-bucket totals + base offsets ----------------

__global__ __launch_bounds__(256) void btot_kernel(const int* __restrict__ seg_cnt, int* __restrict__ btot) {
    int b = blockIdx.x, t = threadIdx.x;
    int s = 0;
    for (int j = t; j < NBLK; j += 256) s += seg_cnt[(size_t)j * NBUCK + b];
    for (int off = 32; off; off >>= 1) s += __shfl_down(s, off);
    __shared__ int ws[4];
    int lane = t & 63, w = t >> 6;
    if (lane == 0) ws[w] = s;
    __syncthreads();
    if (t == 0) btot[b] = ws[0] + ws[1] + ws[2] + ws[3];
}

__global__ __launch_bounds__(256) void bbase_kernel(const int* __restrict__ btot, int* __restrict__ bbase) {
    int t = threadIdx.x;
    int lane = t & 63, w = t >> 6;
    int v = (t < NBUCK) ? btot[t] : 0;
    int x = v;
#pragma unroll
    for (int off = 1; off < 64; off <<= 1) {
        int u = __shfl_up(x, off);
        if (lane >= off) x += u;
    }
    __shared__ int wt[4];
    if (lane == 63) wt[w] = x;
    __syncthreads();
    int add = 0;
#pragma unroll
    for (int k = 0; k < 3; ++k) if (k < w) add += wt[k];
    x += add;
    if (t < NBUCK) bbase[t] = x - v;   // exclusive
}

// ---------------- per-bucket build: count -> offs -> scatter augmented CSR ----------------
// csr2[e] = { src, α_src packed 2×bf16 (layer-1 values, refreshed by aug_kernel for layer 2) }

__global__ __launch_bounds__(1024) void bucket_build(const unsigned* __restrict__ pairs,
                                                     const int* __restrict__ seg_start,
                                                     const int* __restrict__ seg_cnt,
                                                     const int* __restrict__ bbase,
                                                     const float* __restrict__ asrc,
                                                     int* __restrict__ offs,
                                                     uint2* __restrict__ csr2) {
    int b = blockIdx.x, t = threadIdx.x;
    int nodeBase = b << 9;
    __shared__ int cur[512];
    __shared__ int pref[NBLK];
    __shared__ int sstart[NBLK];
    __shared__ int wt2[16];

    if (t < 512) cur[t] = 0;
    for (int j = t; j < NBLK; j += 1024) {
        pref[j]   = seg_cnt[(size_t)j * NBUCK + b];
        sstart[j] = seg_start[(size_t)j * NBUCK + b];
    }
    __syncthreads();
    for (int off = 1; off < NBLK; off <<= 1) {
        int v = 0;
        if (t < NBLK && t >= off) v = pref[t - off];
        __syncthreads();
        if (t < NBLK) pref[t] += v;
        __syncthreads();
    }
    int M = pref[NBLK - 1];

    for (int j = t; j < M; j += 1024) {
        int lo = 0, hi = NBLK - 1;
        while (lo < hi) { int mid = (lo + hi) >> 1; if (pref[mid] > j) hi = mid; else lo = mid + 1; }
        int within = j - (lo ? pref[lo - 1] : 0);
        unsigned wd = pairs[(size_t)lo * CHUNK + sstart[lo] + within];
        atomicAdd(&cur[wd & 511u], 1);
    }
    __syncthreads();

    int lane = t & 63, w = t >> 6;
    int myc = (t < 512) ? cur[t] : 0;
    int x = myc;
#pragma unroll
    for (int off = 1; off < 64; off <<= 1) {
        int u = __shfl_up(x, off);
        if (lane >= off) x += u;
    }
    if (lane == 63) wt2[w] = x;
    __syncthreads();
    int add = 0;
#pragma unroll
    for (int k = 0; k < 15; ++k) if (k < w) add += wt2[k];
    x += add;
    int gstart = bbase[b] + x - myc;
    if (t < 512) {
        if (nodeBase + t <= N_NODES) offs[nodeBase + t] = gstart;
        cur[t] = gstart;
    }
    __syncthreads();

    for (int j = t; j < M; j += 1024) {
        int lo = 0, hi = NBLK - 1;
        while (lo < hi) { int mid = (lo + hi) >> 1; if (pref[mid] > j) hi = mid; else lo = mid + 1; }
        int within = j - (lo ? pref[lo - 1] : 0);
        unsigned wd = pairs[(size_t)lo * CHUNK + sstart[lo] + within];
        int pos = atomicAdd(&cur[wd & 511u], 1);
        unsigned s = wd >> 9;
        float2 av = *(const float2*)&asrc[(size_t)s * 2];
        unsigned ap = (unsigned)f2bf_rne(av.x) | ((unsigned)f2bf_rne(av.y) << 16);
        csr2[pos] = make_uint2(s, ap);
    }
}

// ---------------- refresh csr2 alpha for layer 2 (sequential, L2-resident gather) ----------

__global__ __launch_bounds__(256) void aug_kernel(uint2* __restrict__ csr2, const float* __restrict__ asrc) {
    int e = blockIdx.x * 256 + threadIdx.x;
    if (e >= TOT_E) return;
    unsigned s = csr2[e].x;
    float2 av = *(const float2*)&asrc[(size_t)s * 2];
    csr2[e].y = (unsigned)f2bf_rne(av.x) | ((unsigned)f2bf_rne(av.y) << 16);
}

// ---------------- W -> bf16, fragment-ready layout (both weights) ----------------

__global__ __launch_bounds__(256) void wtconv_both(const float* __restrict__ W1, const float* __restrict__ W2,
                                                   unsigned short* __restrict__ Wt1, unsigned short* __restrict__ Wt2) {
    int i = blockIdx.x * 256 + threadIdx.x;
    const float* W = (i < F_IN * HC) ? W1 : W2;
    unsigned short* Wt = (i < F_IN * HC) ? Wt1 : Wt2;
    int j = (i < F_IN * HC) ? i : i - F_IN * HC;
    if (j < F_IN * HC) {
        int k = j >> 7, col = j & 127;
        Wt[(size_t)(k >> 3) * (HC * 8) + col * 8 + (k & 7)] = f2bf_rne(W[j]);
    }
}

// ---------------- aggregation: augmented CSR (src+α in one sequential 8 B word) -----------
// 4 edge slots × 16 lanes; q = lane&15 holds channels q*8..q*8+7 (8 fp8 = uint2); head=q>>3.
// Per edge: ONE random gather (h row). α comes from the coalesced csr2 stream. f32x2
// accumulators bait v_pk_fma_f32. Reduction xor16+xor32 (9 scalars, 2 steps).

__global__ __launch_bounds__(256) void agg_kernel(const int* __restrict__ offs, const uint2* __restrict__ csr2,
                                                  const float* __restrict__ adst,
                                                  const unsigned char* __restrict__ Hin,
                                                  const float* __restrict__ bias,
                                                  unsigned short* __restrict__ Hout, int do_relu) {
    int wid  = (blockIdx.x * 256 + threadIdx.x) >> 6;
    int lane = threadIdx.x & 63;
    if (wid >= N_NODES) return;
    int beg = offs[wid], end = offs[wid + 1];
    int grp  = lane >> 4;          // edge slot 0..3
    int q    = lane & 15;          // channels q*8 .. q*8+7
    int head = q >> 3;
    float madst = adst[(size_t)wid * 2 + head];
    const unsigned char* hbase = Hin + q * 8;

    float den = 0.f;
    f32x2 ac01 = {0.f, 0.f}, ac23 = {0.f, 0.f}, ac45 = {0.f, 0.f}, ac67 = {0.f, 0.f};

    for (int e = beg + grp; e < end; e += 8) {
        int en = e + 4;
        bool v1 = en < end;
        uint2 c0 = csr2[e];
        uint2 c1 = v1 ? csr2[en] : c0;
        float aa0 = bf2f(head ? (c0.y >> 16) : (c0.y & 0xffffu));
        float aa1 = bf2f(head ? (c1.y >> 16) : (c1.y & 0xffffu));
        uint2 g0 = *(const uint2*)&hbase[(size_t)c0.x * HC];
        uint2 g1 = *(const uint2*)&hbase[(size_t)c1.x * HC];
        float l0 = aa0 + madst; l0 = l0 > 0.f ? l0 : NEG_SLOPE * l0;
        float l1 = aa1 + madst; l1 = l1 > 0.f ? l1 : NEG_SLOPE * l1;
        float w0 = __expf(l0);
        float w1 = v1 ? __expf(l1) : 0.f;
        den += w0 + w1;
        f32x2 w0v = {w0, w0}, w1v = {w1, w1};
        ac01 += __builtin_amdgcn_cvt_pk_f32_fp8(g0.x, 0) * w0v;
        ac23 += __builtin_amdgcn_cvt_pk_f32_fp8(g0.x, 1) * w0v;
        ac45 += __builtin_amdgcn_cvt_pk_f32_fp8(g0.y, 0) * w0v;
        ac67 += __builtin_amdgcn_cvt_pk_f32_fp8(g0.y, 1) * w0v;
        ac01 += __builtin_amdgcn_cvt_pk_f32_fp8(g1.x, 0) * w1v;
        ac23 += __builtin_amdgcn_cvt_pk_f32_fp8(g1.x, 1) * w1v;
        ac45 += __builtin_amdgcn_cvt_pk_f32_fp8(g1.y, 0) * w1v;
        ac67 += __builtin_amdgcn_cvt_pk_f32_fp8(g1.y, 1) * w1v;
    }

    float a0c = ac01.x, a1c = ac01.y, a2c = ac23.x, a3c = ac23.y;
    float a4c = ac45.x, a5c = ac45.y, a6c = ac67.x, a7c = ac67.y;
#pragma unroll
    for (int off = 16; off <= 32; off <<= 1) {
        den += __shfl_xor(den, off);
        a0c += __shfl_xor(a0c, off);
        a1c += __shfl_xor(a1c, off);
        a2c += __shfl_xor(a2c, off);
        a3c += __shfl_xor(a3c, off);
        a4c += __shfl_xor(a4c, off);
        a5c += __shfl_xor(a5c, off);
        a6c += __shfl_xor(a6c, off);
        a7c += __shfl_xor(a7c, off);
    }

    if (lane < 16) {
        float inv = 1.0f / den;
        float4 b0 = *(const float4*)&bias[q * 8];
        float4 b1 = *(const float4*)&bias[q * 8 + 4];
        float o0 = fmaf(a0c, inv, b0.x);
        float o1 = fmaf(a1c, inv, b0.y);
        float o2 = fmaf(a2c, inv, b0.z);
        float o3 = fmaf(a3c, inv, b0.w);
        float o4 = fmaf(a4c, inv, b1.x);
        float o5 = fmaf(a5c, inv, b1.y);
        float o6 = fmaf(a6c, inv, b1.z);
        float o7 = fmaf(a7c, inv, b1.w);
        if (do_relu) {
            o0 = fmaxf(o0, 0.f); o1 = fmaxf(o1, 0.f); o2 = fmaxf(o2, 0.f); o3 = fmaxf(o3, 0.f);
            o4 = fmaxf(o4, 0.f); o5 = fmaxf(o5, 0.f); o6 = fmaxf(o6, 0.f); o7 = fmaxf(o7, 0.f);
        }
        uint4 st;
        st.x = (unsigned)f2bf_rne(o0) | ((unsigned)f2bf_rne(o1) << 16);
        st.y = (unsigned)f2bf_rne(o2) | ((unsigned)f2bf_rne(o3) << 16);
        st.z = (unsigned)f2bf_rne(o4) | ((unsigned)f2bf_rne(o5) << 16);
        st.w = (unsigned)f2bf_rne(o6) | ((unsigned)f2bf_rne(o7) << 16);
        *(uint4*)&Hout[(size_t)wid * HC + q * 8] = st;
    }
}

// ---------------- mean pool (bf16 input; 8K atomics only) ----------------

__global__ __launch_bounds__(256) void pool_kernel(const unsigned short* __restrict__ H2,
                                                   const int* __restrict__ counts,
                                                   float* __restrict__ out) {
    int g = blockIdx.x;
    int chunk = blockIdx.y;
    __shared__ int soff, scnt;
    if (threadIdx.x == 0) {
        int s = 0;
        for (int i = 0; i < g; ++i) s += counts[i];
        soff = s; scnt = counts[g];
    }
    __syncthreads();
    int start = soff, cnt = scnt;
    int r = threadIdx.x >> 7;
    int c = threadIdx.x & 127;
    float acc = 0.f;
    for (int v = chunk * 2 + r; v < cnt; v += 16)
        acc += bf2f((unsigned)H2[(size_t)(start + v) * HC + c]);
    float inv = 1.0f / fmaxf((float)cnt, 1.0f);
    atomicAdd(&out[g * HC + c], acc * inv);
}

// ---------------- launch ----------------

extern "C" void kernel_launch(void* const* d_in, const int* in_sizes, int n_in,
                              void* d_out, int out_size, void* d_ws, size_t ws_size,
                              hipStream_t stream) {
    const float* x     = (const float*)d_in[0];
    const int*   ei    = (const int*)d_in[1];
    const int*   batch = (const int*)d_in[2];
    const float* W1    = (const float*)d_in[3];
    const float* a1s   = (const float*)d_in[4];
    const float* a1d   = (const float*)d_in[5];
    const float* b1    = (const float*)d_in[6];
    const float* W2    = (const float*)d_in[7];
    const float* a2s   = (const float*)d_in[8];
    const float* a2d   = (const float*)d_in[9];
    const float* b2    = (const float*)d_in[10];
    float* out = (float*)d_out;

    char* ws = (char*)d_ws;
    const size_t NH = (size_t)N_NODES * HC;
    unsigned char* hA = (unsigned char*)ws;                 // fp8 gather table, 12.8 MB
    unsigned short* hB = (unsigned short*)(ws + NH);        // bf16, 25.6 MB
    unsigned* pairs = (unsigned*)(hB + NH);                 // 6.8 MB
    float* asrc = (float*)(pairs + (size_t)NBLK * CHUNK);
    float* adst = asrc + (size_t)N_NODES * 2;
    unsigned short* wt1 = (unsigned short*)(adst + (size_t)N_NODES * 2);
    unsigned short* wt2 = wt1 + F_IN * HC;
    int*   offs = (int*)(wt2 + F_IN * HC);
    uint2* csr2 = (uint2*)(offs + (N_NODES + 2));           // 13.6 MB (8-byte aligned)
    int*   seg_start = (int*)(csr2 + TOT_E);
    int*   seg_cnt   = seg_start + (size_t)NBLK * NBUCK;
    int*   btot = seg_cnt + (size_t)NBLK * NBUCK;
    int*   bbase = btot + NBUCK;
    int*   counts = bbase + NBUCK;

    hipMemsetAsync(counts, 0, NGRAPH * sizeof(int), stream);
    hipMemsetAsync(out, 0, (size_t)out_size * sizeof(float), stream);

    // weights -> bf16 fragment layout (both layers, one launch)
    wtconv_both<<<(2 * F_IN * HC + 255) / 256, 256, 0, stream>>>(W1, W2, wt1, wt2);

    // fused: gemm1(+alpha) ⊗ binpart ⊗ counts
    fused_main<<<GEMM_B + NBLK + CNT_B, 256, 0, stream>>>(x, wt1, hA, a1s, a1d, asrc, adst,
                                                          ei, pairs, seg_start, seg_cnt,
                                                          batch, counts);

    // CSR finalize (augmented with layer-1 alpha)
    btot_kernel<<<NBUCK, 256, 0, stream>>>(seg_cnt, btot);
    bbase_kernel<<<1, 256, 0, stream>>>(btot, bbase);
    bucket_build<<<NBUCK, 1024, 0, stream>>>(pairs, seg_start, seg_cnt, bbase, asrc, offs, csr2);

    int waveBlocks = (N_NODES + 3) / 4;
    int augBlocks  = (TOT_E + 255) / 256;

    // layer 1 aggregation
    agg_kernel<<<waveBlocks, 256, 0, stream>>>(offs, csr2, adst, hA, b1, hB, 1);

    // layer 2
    gemm2_kernel<<<GEMM_B, 256, 0, stream>>>(hB, wt2, hA, a2s, a2d, asrc, adst);
    aug_kernel<<<augBlocks, 256, 0, stream>>>(csr2, asrc);
    agg_kernel<<<waveBlocks, 256, 0, stream>>>(offs, csr2, adst, hA, b2, hB, 0);

    // pool
    pool_kernel<<<dim3(NGRAPH, 8), 256, 0, stream>>>(hB, counts, out);
}

// Round 15
// 257.697 us; speedup vs baseline: 1.0031x; 1.0031x over previous
//
#include <hip/hip_runtime.h>

#define N_NODES 100000
#define N_EDGES 1600000
#define F_IN    128
#define HC      128     // H * C
#define NGRAPH  64
#define NEG_SLOPE 0.2f

static constexpr int TOT_E = N_EDGES + N_NODES;         // with self loops

// CSR binned build
#define CHUNK  2048
#define NBLK   831            // ceil(TOT_E / CHUNK)
#define NBUCK  196            // ceil(N_NODES / 512), bucket = dst >> 9

#define GEMM_B 1563           // ceil(N_NODES / 64)
#define CNT_B  391            // ceil(N_NODES / 256)

typedef __bf16 bf16x8 __attribute__((ext_vector_type(8)));
typedef float  f32x4  __attribute__((ext_vector_type(4)));
typedef float  f32x2  __attribute__((ext_vector_type(2)));

__device__ __forceinline__ unsigned short f2bf_rne(float f) {
    unsigned u = __float_as_uint(f);
    u += 0x7fffu + ((u >> 16) & 1u);
    return (unsigned short)(u >> 16);
}
__device__ __forceinline__ float bf2f(unsigned b) {        // low 16 bits used
    return __uint_as_float(b << 16);
}
__device__ __forceinline__ unsigned char f2fp8(float f) {  // OCP e4m3, HW RNE
    return (unsigned char)(__builtin_amdgcn_cvt_pk_fp8_f32(f, f, 0, 0) & 0xff);
}
__device__ __forceinline__ unsigned packal(float2 av) {
    return (unsigned)f2bf_rne(av.x) | ((unsigned)f2bf_rne(av.y) << 16);
}

// ---------------- device bodies ----------------

// binned partition: edges -> block-local bucket-grouped packed pairs. word = (src<<9)|(dst&511)
__device__ __forceinline__ void binpart_body(int blk, int t,
                                             const int* __restrict__ ei,
                                             unsigned* __restrict__ pairs,
                                             int* __restrict__ seg_start,
                                             int* __restrict__ seg_cnt,
                                             int* cnt, int* wtot) {
    int lane = t & 63, w = t >> 6;
    long base = (long)blk * CHUNK;

    cnt[t] = 0;
    __syncthreads();

    for (int j = t; j < CHUNK; j += 256) {
        long i = base + j;
        int d = -1;
        if (i < N_EDGES)    d = ei[N_EDGES + i];
        else if (i < TOT_E) d = (int)(i - N_EDGES);
        if (d >= 0) atomicAdd(&cnt[d >> 9], 1);
    }
    __syncthreads();

    int c = cnt[t];
    int x = c;
#pragma unroll
    for (int off = 1; off < 64; off <<= 1) {
        int v = __shfl_up(x, off);
        if (lane >= off) x += v;
    }
    if (lane == 63) wtot[w] = x;
    __syncthreads();
    int add = 0;
#pragma unroll
    for (int k = 0; k < 3; ++k) if (k < w) add += wtot[k];
    x += add;
    int st = x - c;
    if (t < NBUCK) {
        seg_start[(size_t)blk * NBUCK + t] = st;
        seg_cnt[(size_t)blk * NBUCK + t]   = c;
    }
    __syncthreads();
    cnt[t] = st;
    __syncthreads();

    for (int j = t; j < CHUNK; j += 256) {
        long i = base + j;
        int s = -1, d = -1;
        if (i < N_EDGES)    { s = ei[i]; d = ei[N_EDGES + i]; }
        else if (i < TOT_E) { s = (int)(i - N_EDGES); d = s; }
        if (d >= 0) {
            int pos = atomicAdd(&cnt[d >> 9], 1);
            pairs[base + pos] = ((unsigned)s << 9) | ((unsigned)d & 511u);
        }
    }
}

// GEMM tile + fused alpha epilogue. H stored fp8 e4m3 (gather table); alpha from fp32 acc.
template<bool BF16IN>
__device__ __forceinline__ void gemm_body(int gbid, int t,
                                          const void* __restrict__ Xv,
                                          const unsigned short* __restrict__ Wt,
                                          unsigned char* __restrict__ Hout,
                                          const float* __restrict__ a_src,
                                          const float* __restrict__ a_dst,
                                          float* __restrict__ asrc,
                                          float* __restrict__ adst,
                                          unsigned short* A_lds) {
    int lane = t & 63, wave = t >> 6;
    int wc = wave & 1, wr = wave >> 1;
    int base = gbid * 64;

    bf16x8 Bf[4][4];
    {
        int colb = wc * 64 + (lane & 15);
        int kbb  = lane >> 4;
#pragma unroll
        for (int ct = 0; ct < 4; ++ct)
#pragma unroll
            for (int ks = 0; ks < 4; ++ks) {
                int kb = kbb + 4 * ks;
                Bf[ct][ks] = *(const bf16x8*)&Wt[(size_t)kb * (HC * 8) + (colb + ct * 16) * 8];
            }
    }

#pragma unroll
    for (int it = 0; it < 8; ++it) {
        int i = t + it * 256;
        int row = i >> 5, c4 = i & 31, k0 = c4 * 4;
        uint2 pk; pk.x = 0; pk.y = 0;
        if (base + row < N_NODES) {
            if (BF16IN) {
                pk = ((const uint2*)Xv)[(size_t)(base + row) * 32 + c4];
            } else {
                float4 v = ((const float4*)Xv)[(size_t)(base + row) * 32 + c4];
                pk.x = (unsigned)f2bf_rne(v.x) | ((unsigned)f2bf_rne(v.y) << 16);
                pk.y = (unsigned)f2bf_rne(v.z) | ((unsigned)f2bf_rne(v.w) << 16);
            }
        }
        int byte = row * 256 + (((k0 >> 3) ^ (row & 7)) << 4) + (k0 & 4) * 2;
        *(uint2*)((char*)A_lds + byte) = pk;
    }
    __syncthreads();

    f32x4 acc[2][4] = {};
#pragma unroll
    for (int ks = 0; ks < 4; ++ks) {
        bf16x8 Af[2];
#pragma unroll
        for (int r = 0; r < 2; ++r) {
            int row = wr * 32 + r * 16 + (lane & 15);
            int kb  = ks * 4 + (lane >> 4);
            int byte = row * 256 + ((kb ^ (row & 7)) << 4);
            Af[r] = *(const bf16x8*)((const char*)A_lds + byte);
        }
#pragma unroll
        for (int ct = 0; ct < 4; ++ct) {
            acc[0][ct] = __builtin_amdgcn_mfma_f32_16x16x32_bf16(Af[0], Bf[ct][ks], acc[0][ct], 0, 0, 0);
            acc[1][ct] = __builtin_amdgcn_mfma_f32_16x16x32_bf16(Af[1], Bf[ct][ks], acc[1][ct], 0, 0, 0);
        }
    }

    // H store (fp8 e4m3)
#pragma unroll
    for (int r = 0; r < 2; ++r) {
        int row0 = base + wr * 32 + r * 16 + (lane >> 4) * 4;
#pragma unroll
        for (int reg = 0; reg < 4; ++reg) {
            int row = row0 + reg;
            if (row < N_NODES) {
#pragma unroll
                for (int ct = 0; ct < 4; ++ct) {
                    int col = wc * 64 + ct * 16 + (lane & 15);
                    Hout[(size_t)row * HC + col] = f2fp8(acc[r][ct][reg]);
                }
            }
        }
    }

    // fused alpha (exact fp32 acc)
    float as_c[4], ad_c[4];
#pragma unroll
    for (int ct = 0; ct < 4; ++ct) {
        int ch = wc * 64 + ct * 16 + (lane & 15);
        as_c[ct] = a_src[ch];
        ad_c[ct] = a_dst[ch];
    }
#pragma unroll
    for (int r = 0; r < 2; ++r) {
#pragma unroll
        for (int reg = 0; reg < 4; ++reg) {
            float ps = acc[r][0][reg] * as_c[0] + acc[r][1][reg] * as_c[1]
                     + acc[r][2][reg] * as_c[2] + acc[r][3][reg] * as_c[3];
            float pd = acc[r][0][reg] * ad_c[0] + acc[r][1][reg] * ad_c[1]
                     + acc[r][2][reg] * ad_c[2] + acc[r][3][reg] * ad_c[3];
#pragma unroll
            for (int off = 1; off < 16; off <<= 1) {
                ps += __shfl_xor(ps, off);
                pd += __shfl_xor(pd, off);
            }
            if ((lane & 15) == 0) {
                int row = base + wr * 32 + r * 16 + (lane >> 4) * 4 + reg;
                if (row < N_NODES) {
                    asrc[(size_t)row * 2 + wc] = ps;
                    adst[(size_t)row * 2 + wc] = pd;
                }
            }
        }
    }
}

// ---------------- fused main: gemm1 ⊗ binpart ⊗ counts ----------------

__global__ __launch_bounds__(256) void fused_main(const float* __restrict__ x,
                                                  const unsigned short* __restrict__ wt1,
                                                  unsigned char* __restrict__ hA,
                                                  const float* __restrict__ a1s,
                                                  const float* __restrict__ a1d,
                                                  float* __restrict__ asrc,
                                                  float* __restrict__ adst,
                                                  const int* __restrict__ ei,
                                                  unsigned* __restrict__ pairs,
                                                  int* __restrict__ seg_start,
                                                  int* __restrict__ seg_cnt,
                                                  const int* __restrict__ batch,
                                                  int* __restrict__ counts) {
    __shared__ unsigned short A_lds[64 * F_IN];   // 16 KB (gemm branch)
    __shared__ int cnt[256];                      // binpart branch
    __shared__ int wtot[4];
    __shared__ int loc[NGRAPH];                   // counts branch
    int bid = blockIdx.x, t = threadIdx.x;

    if (bid < 2 * NBLK) {
        if (bid & 1) binpart_body(bid >> 1, t, ei, pairs, seg_start, seg_cnt, cnt, wtot);
        else         gemm_body<false>(bid >> 1, t, x, wt1, hA, a1s, a1d, asrc, adst, A_lds);
    } else if (bid < NBLK + GEMM_B) {
        gemm_body<false>(bid - NBLK, t, x, wt1, hA, a1s, a1d, asrc, adst, A_lds);
    } else {
        int cb = bid - (NBLK + GEMM_B);
        if (t < NGRAPH) loc[t] = 0;
        __syncthreads();
        int i = cb * 256 + t;
        if (i < N_NODES) atomicAdd(&loc[batch[i]], 1);
        __syncthreads();
        if (t < NGRAPH && loc[t]) atomicAdd(&counts[t], loc[t]);
    }
}

// ---------------- standalone gemm (layer 2: bf16 in, fp8 out) ----------------

__global__ __launch_bounds__(256) void gemm2_kernel(const unsigned short* __restrict__ Xv,
                                                    const unsigned short* __restrict__ Wt,
                                                    unsigned char* __restrict__ Hout,
                                                    const float* __restrict__ a_src,
                                                    const float* __restrict__ a_dst,
                                                    float* __restrict__ asrc,
                                                    float* __restrict__ adst) {
    __shared__ unsigned short A_lds[64 * F_IN];
    gemm_body<true>(blockIdx.x, threadIdx.x, Xv, Wt, Hout, a_src, a_dst, asrc, adst, A_lds);
}

// ---------------- per-bucket totals + base offsets ----------------

__global__ __launch_bounds__(256) void btot_kernel(const int* __restrict__ seg_cnt, int* __restrict__ btot) {
    int b = blockIdx.x, t = threadIdx.x;
    int s = 0;
    for (int j = t; j < NBLK; j += 256) s += seg_cnt[(size_t)j * NBUCK + b];
    for (int off = 32; off; off >>= 1) s += __shfl_down(s, off);
    __shared__ int ws[4];
    int lane = t & 63, w = t >> 6;
    if (lane == 0) ws[w] = s;
    __syncthreads();
    if (t == 0) btot[b] = ws[0] + ws[1] + ws[2] + ws[3];
}

__global__ __launch_bounds__(256) void bbase_kernel(const int* __restrict__ btot, int* __restrict__ bbase) {
    int t = threadIdx.x;
    int lane = t & 63, w = t >> 6;
    int v = (t < NBUCK) ? btot[t] : 0;
    int x = v;
#pragma unroll
    for (int off = 1; off < 64; off <<= 1) {
        int u = __shfl_up(x, off);
        if (lane >= off) x += u;
    }
    __shared__ int wt[4];
    if (lane == 63) wt[w] = x;
    __syncthreads();
    int add = 0;
#pragma unroll
    for (int k = 0; k < 3; ++k) if (k < w) add += wt[k];
    x += add;
    if (t < NBUCK) bbase[t] = x - v;   // exclusive
}

// ---------------- per-bucket build: count -> offs -> scatter -> alpha pass ----------------
// scatter writes lean 4 B csr_src; pass 3 fills csr_al (layer-1 alpha, packed 2xbf16) over
// the block's own L2-hot window.

__global__ __launch_bounds__(1024) void bucket_build(const unsigned* __restrict__ pairs,
                                                     const int* __restrict__ seg_start,
                                                     const int* __restrict__ seg_cnt,
                                                     const int* __restrict__ bbase,
                                                     const float* __restrict__ asrc,
                                                     int* __restrict__ offs,
                                                     int* __restrict__ csr_src,
                                                     unsigned* __restrict__ csr_al) {
    int b = blockIdx.x, t = threadIdx.x;
    int nodeBase = b << 9;
    __shared__ int cur[512];
    __shared__ int pref[NBLK];
    __shared__ int sstart[NBLK];
    __shared__ int wt2[16];

    if (t < 512) cur[t] = 0;
    for (int j = t; j < NBLK; j += 1024) {
        pref[j]   = seg_cnt[(size_t)j * NBUCK + b];
        sstart[j] = seg_start[(size_t)j * NBUCK + b];
    }
    __syncthreads();
    for (int off = 1; off < NBLK; off <<= 1) {
        int v = 0;
        if (t < NBLK && t >= off) v = pref[t - off];
        __syncthreads();
        if (t < NBLK) pref[t] += v;
        __syncthreads();
    }
    int M = pref[NBLK - 1];

    for (int j = t; j < M; j += 1024) {
        int lo = 0, hi = NBLK - 1;
        while (lo < hi) { int mid = (lo + hi) >> 1; if (pref[mid] > j) hi = mid; else lo = mid + 1; }
        int within = j - (lo ? pref[lo - 1] : 0);
        unsigned wd = pairs[(size_t)lo * CHUNK + sstart[lo] + within];
        atomicAdd(&cur[wd & 511u], 1);
    }
    __syncthreads();

    int lane = t & 63, w = t >> 6;
    int myc = (t < 512) ? cur[t] : 0;
    int x = myc;
#pragma unroll
    for (int off = 1; off < 64; off <<= 1) {
        int u = __shfl_up(x, off);
        if (lane >= off) x += u;
    }
    if (lane == 63) wt2[w] = x;
    __syncthreads();
    int add = 0;
#pragma unroll
    for (int k = 0; k < 15; ++k) if (k < w) add += wt2[k];
    x += add;
    int gstart = bbase[b] + x - myc;
    if (t < 512) {
        if (nodeBase + t <= N_NODES) offs[nodeBase + t] = gstart;
        cur[t] = gstart;
    }
    __syncthreads();

    for (int j = t; j < M; j += 1024) {
        int lo = 0, hi = NBLK - 1;
        while (lo < hi) { int mid = (lo + hi) >> 1; if (pref[mid] > j) hi = mid; else lo = mid + 1; }
        int within = j - (lo ? pref[lo - 1] : 0);
        unsigned wd = pairs[(size_t)lo * CHUNK + sstart[lo] + within];
        int pos = atomicAdd(&cur[wd & 511u], 1);
        csr_src[pos] = (int)(wd >> 9);
    }
    __syncthreads();

    // pass 3: layer-1 alpha stream over this block's window (L2-hot reads)
    int wbase = bbase[b];
    for (int j = t; j < M; j += 1024) {
        unsigned s = (unsigned)csr_src[wbase + j];
        float2 av = *(const float2*)&asrc[(size_t)s * 2];
        csr_al[wbase + j] = packal(av);
    }
}

// ---------------- layer-2 alpha stream (sequential read/write, L2-resident gather) --------

__global__ __launch_bounds__(256) void alq_kernel(const int* __restrict__ csr_src,
                                                  const float* __restrict__ asrc,
                                                  unsigned* __restrict__ csr_al) {
    int e = blockIdx.x * 256 + threadIdx.x;
    if (e >= TOT_E) return;
    unsigned s = (unsigned)csr_src[e];
    float2 av = *(const float2*)&asrc[(size_t)s * 2];
    csr_al[e] = packal(av);
}

// ---------------- W -> bf16, fragment-ready layout (both weights) ----------------

__global__ __launch_bounds__(256) void wtconv_both(const float* __restrict__ W1, const float* __restrict__ W2,
                                                   unsigned short* __restrict__ Wt1, unsigned short* __restrict__ Wt2) {
    int i = blockIdx.x * 256 + threadIdx.x;
    const float* W = (i < F_IN * HC) ? W1 : W2;
    unsigned short* Wt = (i < F_IN * HC) ? Wt1 : Wt2;
    int j = (i < F_IN * HC) ? i : i - F_IN * HC;
    if (j < F_IN * HC) {
        int k = j >> 7, col = j & 127;
        Wt[(size_t)(k >> 3) * (HC * 8) + col * 8 + (k & 7)] = f2bf_rne(W[j]);
    }
}

// ---------------- aggregation: sequential src+alpha streams, one random h gather/edge -----
// 4 edge slots × 16 lanes; q = lane&15 holds channels q*8..q*8+7 (8 fp8 = uint2); head=q>>3.

__global__ __launch_bounds__(256) void agg_kernel(const int* __restrict__ offs,
                                                  const int* __restrict__ csr_src,
                                                  const unsigned* __restrict__ csr_al,
                                                  const float* __restrict__ adst,
                                                  const unsigned char* __restrict__ Hin,
                                                  const float* __restrict__ bias,
                                                  unsigned short* __restrict__ Hout, int do_relu) {
    int wid  = (blockIdx.x * 256 + threadIdx.x) >> 6;
    int lane = threadIdx.x & 63;
    if (wid >= N_NODES) return;
    int beg = offs[wid], end = offs[wid + 1];
    int grp  = lane >> 4;          // edge slot 0..3
    int q    = lane & 15;          // channels q*8 .. q*8+7
    int head = q >> 3;
    float madst = adst[(size_t)wid * 2 + head];
    const unsigned char* hbase = Hin + q * 8;

    float den = 0.f;
    f32x2 ac01 = {0.f, 0.f}, ac23 = {0.f, 0.f}, ac45 = {0.f, 0.f}, ac67 = {0.f, 0.f};

    for (int e = beg + grp; e < end; e += 8) {
        int en = e + 4;
        bool v1 = en < end;
        int s0 = csr_src[e];
        int s1 = v1 ? csr_src[en] : s0;
        unsigned al0 = csr_al[e];
        unsigned al1 = v1 ? csr_al[en] : 0u;
        float aa0 = bf2f(head ? (al0 >> 16) : (al0 & 0xffffu));
        float aa1 = bf2f(head ? (al1 >> 16) : (al1 & 0xffffu));
        uint2 g0 = *(const uint2*)&hbase[(size_t)s0 * HC];
        uint2 g1 = *(const uint2*)&hbase[(size_t)s1 * HC];
        float l0 = aa0 + madst; l0 = l0 > 0.f ? l0 : NEG_SLOPE * l0;
        float l1 = aa1 + madst; l1 = l1 > 0.f ? l1 : NEG_SLOPE * l1;
        float w0 = __expf(l0);
        float w1 = v1 ? __expf(l1) : 0.f;
        den += w0 + w1;
        f32x2 w0v = {w0, w0}, w1v = {w1, w1};
        ac01 += __builtin_amdgcn_cvt_pk_f32_fp8(g0.x, 0) * w0v;
        ac23 += __builtin_amdgcn_cvt_pk_f32_fp8(g0.x, 1) * w0v;
        ac45 += __builtin_amdgcn_cvt_pk_f32_fp8(g0.y, 0) * w0v;
        ac67 += __builtin_amdgcn_cvt_pk_f32_fp8(g0.y, 1) * w0v;
        ac01 += __builtin_amdgcn_cvt_pk_f32_fp8(g1.x, 0) * w1v;
        ac23 += __builtin_amdgcn_cvt_pk_f32_fp8(g1.x, 1) * w1v;
        ac45 += __builtin_amdgcn_cvt_pk_f32_fp8(g1.y, 0) * w1v;
        ac67 += __builtin_amdgcn_cvt_pk_f32_fp8(g1.y, 1) * w1v;
    }

    float a0c = ac01.x, a1c = ac01.y, a2c = ac23.x, a3c = ac23.y;
    float a4c = ac45.x, a5c = ac45.y, a6c = ac67.x, a7c = ac67.y;
#pragma unroll
    for (int off = 16; off <= 32; off <<= 1) {
        den += __shfl_xor(den, off);
        a0c += __shfl_xor(a0c, off);
        a1c += __shfl_xor(a1c, off);
        a2c += __shfl_xor(a2c, off);
        a3c += __shfl_xor(a3c, off);
        a4c += __shfl_xor(a4c, off);
        a5c += __shfl_xor(a5c, off);
        a6c += __shfl_xor(a6c, off);
        a7c += __shfl_xor(a7c, off);
    }

    if (lane < 16) {
        float inv = 1.0f / den;
        float4 b0 = *(const float4*)&bias[q * 8];
        float4 b1 = *(const float4*)&bias[q * 8 + 4];
        float o0 = fmaf(a0c, inv, b0.x);
        float o1 = fmaf(a1c, inv, b0.y);
        float o2 = fmaf(a2c, inv, b0.z);
        float o3 = fmaf(a3c, inv, b0.w);
        float o4 = fmaf(a4c, inv, b1.x);
        float o5 = fmaf(a5c, inv, b1.y);
        float o6 = fmaf(a6c, inv, b1.z);
        float o7 = fmaf(a7c, inv, b1.w);
        if (do_relu) {
            o0 = fmaxf(o0, 0.f); o1 = fmaxf(o1, 0.f); o2 = fmaxf(o2, 0.f); o3 = fmaxf(o3, 0.f);
            o4 = fmaxf(o4, 0.f); o5 = fmaxf(o5, 0.f); o6 = fmaxf(o6, 0.f); o7 = fmaxf(o7, 0.f);
        }
        uint4 st;
        st.x = (unsigned)f2bf_rne(o0) | ((unsigned)f2bf_rne(o1) << 16);
        st.y = (unsigned)f2bf_rne(o2) | ((unsigned)f2bf_rne(o3) << 16);
        st.z = (unsigned)f2bf_rne(o4) | ((unsigned)f2bf_rne(o5) << 16);
        st.w = (unsigned)f2bf_rne(o6) | ((unsigned)f2bf_rne(o7) << 16);
        *(uint4*)&Hout[(size_t)wid * HC + q * 8] = st;
    }
}

// ---------------- mean pool (bf16 input; 8K atomics only) ----------------

__global__ __launch_bounds__(256) void pool_kernel(const unsigned short* __restrict__ H2,
                                                   const int* __restrict__ counts,
                                                   float* __restrict__ out) {
    int g = blockIdx.x;
    int chunk = blockIdx.y;
    __shared__ int soff, scnt;
    if (threadIdx.x == 0) {
        int s = 0;
        for (int i = 0; i < g; ++i) s += counts[i];
        soff = s; scnt = counts[g];
    }
    __syncthreads();
    int start = soff, cnt = scnt;
    int r = threadIdx.x >> 7;
    int c = threadIdx.x & 127;
    float acc = 0.f;
    for (int v = chunk * 2 + r; v < cnt; v += 16)
        acc += bf2f((unsigned)H2[(size_t)(start + v) * HC + c]);
    float inv = 1.0f / fmaxf((float)cnt, 1.0f);
    atomicAdd(&out[g * HC + c], acc * inv);
}

// ---------------- launch ----------------

extern "C" void kernel_launch(void* const* d_in, const int* in_sizes, int n_in,
                              void* d_out, int out_size, void* d_ws, size_t ws_size,
                              hipStream_t stream) {
    const float* x     = (const float*)d_in[0];
    const int*   ei    = (const int*)d_in[1];
    const int*   batch = (const int*)d_in[2];
    const float* W1    = (const float*)d_in[3];
    const float* a1s   = (const float*)d_in[4];
    const float* a1d   = (const float*)d_in[5];
    const float* b1    = (const float*)d_in[6];
    const float* W2    = (const float*)d_in[7];
    const float* a2s   = (const float*)d_in[8];
    const float* a2d   = (const float*)d_in[9];
    const float* b2    = (const float*)d_in[10];
    float* out = (float*)d_out;

    char* ws = (char*)d_ws;
    const size_t NH = (size_t)N_NODES * HC;
    unsigned char* hA = (unsigned char*)ws;                 // fp8 gather table, 12.8 MB
    unsigned short* hB = (unsigned short*)(ws + NH);        // bf16, 25.6 MB
    unsigned* pairs = (unsigned*)(hB + NH);                 // 6.8 MB
    float* asrc = (float*)(pairs + (size_t)NBLK * CHUNK);
    float* adst = asrc + (size_t)N_NODES * 2;
    unsigned short* wt1 = (unsigned short*)(adst + (size_t)N_NODES * 2);
    unsigned short* wt2 = wt1 + F_IN * HC;
    int*   offs = (int*)(wt2 + F_IN * HC);
    int*   csr_src = offs + (N_NODES + 2);
    unsigned* csr_al = (unsigned*)(csr_src + TOT_E);
    int*   seg_start = (int*)(csr_al + TOT_E);
    int*   seg_cnt   = seg_start + (size_t)NBLK * NBUCK;
    int*   btot = seg_cnt + (size_t)NBLK * NBUCK;
    int*   bbase = btot + NBUCK;
    int*   counts = bbase + NBUCK;

    hipMemsetAsync(counts, 0, NGRAPH * sizeof(int), stream);
    hipMemsetAsync(out, 0, (size_t)out_size * sizeof(float), stream);

    // weights -> bf16 fragment layout (both layers, one launch)
    wtconv_both<<<(2 * F_IN * HC + 255) / 256, 256, 0, stream>>>(W1, W2, wt1, wt2);

    // fused: gemm1(+alpha) ⊗ binpart ⊗ counts
    fused_main<<<GEMM_B + NBLK + CNT_B, 256, 0, stream>>>(x, wt1, hA, a1s, a1d, asrc, adst,
                                                          ei, pairs, seg_start, seg_cnt,
                                                          batch, counts);

    // CSR finalize (csr_src + layer-1 alpha stream)
    btot_kernel<<<NBUCK, 256, 0, stream>>>(seg_cnt, btot);
    bbase_kernel<<<1, 256, 0, stream>>>(btot, bbase);
    bucket_build<<<NBUCK, 1024, 0, stream>>>(pairs, seg_start, seg_cnt, bbase, asrc,
                                             offs, csr_src, csr_al);

    int waveBlocks = (N_NODES + 3) / 4;
    int augBlocks  = (TOT_E + 255) / 256;

    // layer 1 aggregation
    agg_kernel<<<waveBlocks, 256, 0, stream>>>(offs, csr_src, csr_al, adst, hA, b1, hB, 1);

    // layer 2
    gemm2_kernel<<<GEMM_B, 256, 0, stream>>>(hB, wt2, hA, a2s, a2d, asrc, adst);
    alq_kernel<<<augBlocks, 256, 0, stream>>>(csr_src, asrc, csr_al);
    agg_kernel<<<waveBlocks, 256, 0, stream>>>(offs, csr_src, csr_al, adst, hA, b2, hB, 0);

    // pool
    pool_kernel<<<dim3(NGRAPH, 8), 256, 0, stream>>>(hB, counts, out);
}

// Round 16
// 249.171 us; speedup vs baseline: 1.0374x; 1.0342x over previous
//
#include <hip/hip_runtime.h>

#define N_NODES 100000
#define N_EDGES 1600000
#define F_IN    128
#define HC      128     // H * C
#define NGRAPH  64
#define NEG_SLOPE 0.2f

static constexpr int TOT_E = N_EDGES + N_NODES;         // with self loops

// CSR binned build
#define CHUNK  2048
#define NBLK   831            // ceil(TOT_E / CHUNK)
#define NBUCK  196            // ceil(N_NODES / 512), bucket = dst >> 9

#define GEMM_B 1563           // ceil(N_NODES / 64)
#define CNT_B  391            // ceil(N_NODES / 256)

typedef __bf16 bf16x8 __attribute__((ext_vector_type(8)));
typedef float  f32x4  __attribute__((ext_vector_type(4)));
typedef float  f32x2  __attribute__((ext_vector_type(2)));

__device__ __forceinline__ unsigned short f2bf_rne(float f) {
    unsigned u = __float_as_uint(f);
    u += 0x7fffu + ((u >> 16) & 1u);
    return (unsigned short)(u >> 16);
}
__device__ __forceinline__ float bf2f(unsigned b) {        // low 16 bits used
    return __uint_as_float(b << 16);
}
__device__ __forceinline__ unsigned char f2fp8(float f) {  // OCP e4m3, HW RNE
    return (unsigned char)(__builtin_amdgcn_cvt_pk_fp8_f32(f, f, 0, 0) & 0xff);
}

// ---------------- device bodies ----------------

// binned partition: edges -> block-local bucket-grouped packed pairs. word = (src<<9)|(dst&511)
__device__ __forceinline__ void binpart_body(int blk, int t,
                                             const int* __restrict__ ei,
                                             unsigned* __restrict__ pairs,
                                             int* __restrict__ seg_start,
                                             int* __restrict__ seg_cnt,
                                             int* cnt, int* wtot) {
    int lane = t & 63, w = t >> 6;
    long base = (long)blk * CHUNK;

    cnt[t] = 0;
    __syncthreads();

    for (int j = t; j < CHUNK; j += 256) {
        long i = base + j;
        int d = -1;
        if (i < N_EDGES)    d = ei[N_EDGES + i];
        else if (i < TOT_E) d = (int)(i - N_EDGES);
        if (d >= 0) atomicAdd(&cnt[d >> 9], 1);
    }
    __syncthreads();

    int c = cnt[t];
    int x = c;
#pragma unroll
    for (int off = 1; off < 64; off <<= 1) {
        int v = __shfl_up(x, off);
        if (lane >= off) x += v;
    }
    if (lane == 63) wtot[w] = x;
    __syncthreads();
    int add = 0;
#pragma unroll
    for (int k = 0; k < 3; ++k) if (k < w) add += wtot[k];
    x += add;
    int st = x - c;
    if (t < NBUCK) {
        seg_start[(size_t)blk * NBUCK + t] = st;
        seg_cnt[(size_t)blk * NBUCK + t]   = c;
    }
    __syncthreads();
    cnt[t] = st;
    __syncthreads();

    for (int j = t; j < CHUNK; j += 256) {
        long i = base + j;
        int s = -1, d = -1;
        if (i < N_EDGES)    { s = ei[i]; d = ei[N_EDGES + i]; }
        else if (i < TOT_E) { s = (int)(i - N_EDGES); d = s; }
        if (d >= 0) {
            int pos = atomicAdd(&cnt[d >> 9], 1);
            pairs[base + pos] = ((unsigned)s << 9) | ((unsigned)d & 511u);
        }
    }
}

// GEMM tile + fused alpha epilogue. H stored fp8 e4m3 (gather table); alpha from fp32 acc.
template<bool BF16IN>
__device__ __forceinline__ void gemm_body(int gbid, int t,
                                          const void* __restrict__ Xv,
                                          const unsigned short* __restrict__ Wt,
                                          unsigned char* __restrict__ Hout,
                                          const float* __restrict__ a_src,
                                          const float* __restrict__ a_dst,
                                          float* __restrict__ asrc,
                                          float* __restrict__ adst,
                                          unsigned short* A_lds) {
    int lane = t & 63, wave = t >> 6;
    int wc = wave & 1, wr = wave >> 1;
    int base = gbid * 64;

    bf16x8 Bf[4][4];
    {
        int colb = wc * 64 + (lane & 15);
        int kbb  = lane >> 4;
#pragma unroll
        for (int ct = 0; ct < 4; ++ct)
#pragma unroll
            for (int ks = 0; ks < 4; ++ks) {
                int kb = kbb + 4 * ks;
                Bf[ct][ks] = *(const bf16x8*)&Wt[(size_t)kb * (HC * 8) + (colb + ct * 16) * 8];
            }
    }

#pragma unroll
    for (int it = 0; it < 8; ++it) {
        int i = t + it * 256;
        int row = i >> 5, c4 = i & 31, k0 = c4 * 4;
        uint2 pk; pk.x = 0; pk.y = 0;
        if (base + row < N_NODES) {
            if (BF16IN) {
                pk = ((const uint2*)Xv)[(size_t)(base + row) * 32 + c4];
            } else {
                float4 v = ((const float4*)Xv)[(size_t)(base + row) * 32 + c4];
                pk.x = (unsigned)f2bf_rne(v.x) | ((unsigned)f2bf_rne(v.y) << 16);
                pk.y = (unsigned)f2bf_rne(v.z) | ((unsigned)f2bf_rne(v.w) << 16);
            }
        }
        int byte = row * 256 + (((k0 >> 3) ^ (row & 7)) << 4) + (k0 & 4) * 2;
        *(uint2*)((char*)A_lds + byte) = pk;
    }
    __syncthreads();

    f32x4 acc[2][4] = {};
#pragma unroll
    for (int ks = 0; ks < 4; ++ks) {
        bf16x8 Af[2];
#pragma unroll
        for (int r = 0; r < 2; ++r) {
            int row = wr * 32 + r * 16 + (lane & 15);
            int kb  = ks * 4 + (lane >> 4);
            int byte = row * 256 + ((kb ^ (row & 7)) << 4);
            Af[r] = *(const bf16x8*)((const char*)A_lds + byte);
        }
#pragma unroll
        for (int ct = 0; ct < 4; ++ct) {
            acc[0][ct] = __builtin_amdgcn_mfma_f32_16x16x32_bf16(Af[0], Bf[ct][ks], acc[0][ct], 0, 0, 0);
            acc[1][ct] = __builtin_amdgcn_mfma_f32_16x16x32_bf16(Af[1], Bf[ct][ks], acc[1][ct], 0, 0, 0);
        }
    }

    // H store (fp8 e4m3)
#pragma unroll
    for (int r = 0; r < 2; ++r) {
        int row0 = base + wr * 32 + r * 16 + (lane >> 4) * 4;
#pragma unroll
        for (int reg = 0; reg < 4; ++reg) {
            int row = row0 + reg;
            if (row < N_NODES) {
#pragma unroll
                for (int ct = 0; ct < 4; ++ct) {
                    int col = wc * 64 + ct * 16 + (lane & 15);
                    Hout[(size_t)row * HC + col] = f2fp8(acc[r][ct][reg]);
                }
            }
        }
    }

    // fused alpha (exact fp32 acc)
    float as_c[4], ad_c[4];
#pragma unroll
    for (int ct = 0; ct < 4; ++ct) {
        int ch = wc * 64 + ct * 16 + (lane & 15);
        as_c[ct] = a_src[ch];
        ad_c[ct] = a_dst[ch];
    }
#pragma unroll
    for (int r = 0; r < 2; ++r) {
#pragma unroll
        for (int reg = 0; reg < 4; ++reg) {
            float ps = acc[r][0][reg] * as_c[0] + acc[r][1][reg] * as_c[1]
                     + acc[r][2][reg] * as_c[2] + acc[r][3][reg] * as_c[3];
            float pd = acc[r][0][reg] * ad_c[0] + acc[r][1][reg] * ad_c[1]
                     + acc[r][2][reg] * ad_c[2] + acc[r][3][reg] * ad_c[3];
#pragma unroll
            for (int off = 1; off < 16; off <<= 1) {
                ps += __shfl_xor(ps, off);
                pd += __shfl_xor(pd, off);
            }
            if ((lane & 15) == 0) {
                int row = base + wr * 32 + r * 16 + (lane >> 4) * 4 + reg;
                if (row < N_NODES) {
                    asrc[(size_t)row * 2 + wc] = ps;
                    adst[(size_t)row * 2 + wc] = pd;
                }
            }
        }
    }
}

// ---------------- fused main: gemm1 ⊗ binpart ⊗ counts ----------------

__global__ __launch_bounds__(256) void fused_main(const float* __restrict__ x,
                                                  const unsigned short* __restrict__ wt1,
                                                  unsigned char* __restrict__ hA,
                                                  const float* __restrict__ a1s,
                                                  const float* __restrict__ a1d,
                                                  float* __restrict__ asrc,
                                                  float* __restrict__ adst,
                                                  const int* __restrict__ ei,
                                                  unsigned* __restrict__ pairs,
                                                  int* __restrict__ seg_start,
                                                  int* __restrict__ seg_cnt,
                                                  const int* __restrict__ batch,
                                                  int* __restrict__ counts) {
    __shared__ unsigned short A_lds[64 * F_IN];   // 16 KB (gemm branch)
    __shared__ int cnt[256];                      // binpart branch
    __shared__ int wtot[4];
    __shared__ int loc[NGRAPH];                   // counts branch
    int bid = blockIdx.x, t = threadIdx.x;

    if (bid < 2 * NBLK) {
        if (bid & 1) binpart_body(bid >> 1, t, ei, pairs, seg_start, seg_cnt, cnt, wtot);
        else         gemm_body<false>(bid >> 1, t, x, wt1, hA, a1s, a1d, asrc, adst, A_lds);
    } else if (bid < NBLK + GEMM_B) {
        gemm_body<false>(bid - NBLK, t, x, wt1, hA, a1s, a1d, asrc, adst, A_lds);
    } else {
        int cb = bid - (NBLK + GEMM_B);
        if (t < NGRAPH) loc[t] = 0;
        __syncthreads();
        int i = cb * 256 + t;
        if (i < N_NODES) atomicAdd(&loc[batch[i]], 1);
        __syncthreads();
        if (t < NGRAPH && loc[t]) atomicAdd(&counts[t], loc[t]);
    }
}

// ---------------- standalone gemm (layer 2: bf16 in, fp8 out) ----------------

__global__ __launch_bounds__(256) void gemm2_kernel(const unsigned short* __restrict__ Xv,
                                                    const unsigned short* __restrict__ Wt,
                                                    unsigned char* __restrict__ Hout,
                                                    const float* __restrict__ a_src,
                                                    const float* __restrict__ a_dst,
                                                    float* __restrict__ asrc,
                                                    float* __restrict__ adst) {
    __shared__ unsigned short A_lds[64 * F_IN];
    gemm_body<true>(blockIdx.x, threadIdx.x, Xv, Wt, Hout, a_src, a_dst, asrc, adst, A_lds);
}

// ---------------- per-bucket totals + base offsets ----------------

__global__ __launch_bounds__(256) void btot_kernel(const int* __restrict__ seg_cnt, int* __restrict__ btot) {
    int b = blockIdx.x, t = threadIdx.x;
    int s = 0;
    for (int j = t; j < NBLK; j += 256) s += seg_cnt[(size_t)j * NBUCK + b];
    for (int off = 32; off; off >>= 1) s += __shfl_down(s, off);
    __shared__ int ws[4];
    int lane = t & 63, w = t >> 6;
    if (lane == 0) ws[w] = s;
    __syncthreads();
    if (t == 0) btot[b] = ws[0] + ws[1] + ws[2] + ws[3];
}

__global__ __launch_bounds__(256) void bbase_kernel(const int* __restrict__ btot, int* __restrict__ bbase) {
    int t = threadIdx.x;
    int lane = t & 63, w = t >> 6;
    int v = (t < NBUCK) ? btot[t] : 0;
    int x = v;
#pragma unroll
    for (int off = 1; off < 64; off <<= 1) {
        int u = __shfl_up(x, off);
        if (lane >= off) x += u;
    }
    __shared__ int wt[4];
    if (lane == 63) wt[w] = x;
    __syncthreads();
    int add = 0;
#pragma unroll
    for (int k = 0; k < 3; ++k) if (k < w) add += wt[k];
    x += add;
    if (t < NBUCK) bbase[t] = x - v;   // exclusive
}

// ---------------- per-bucket build: count -> offs -> exact scatter ----------------

__global__ __launch_bounds__(1024) void bucket_build(const unsigned* __restrict__ pairs,
                                                     const int* __restrict__ seg_start,
                                                     const int* __restrict__ seg_cnt,
                                                     const int* __restrict__ bbase,
                                                     int* __restrict__ offs,
                                                     int* __restrict__ csr_src) {
    int b = blockIdx.x, t = threadIdx.x;
    int nodeBase = b << 9;
    __shared__ int cur[512];
    __shared__ int pref[NBLK];
    __shared__ int sstart[NBLK];
    __shared__ int wt2[16];

    if (t < 512) cur[t] = 0;
    for (int j = t; j < NBLK; j += 1024) {
        pref[j]   = seg_cnt[(size_t)j * NBUCK + b];
        sstart[j] = seg_start[(size_t)j * NBUCK + b];
    }
    __syncthreads();
    for (int off = 1; off < NBLK; off <<= 1) {
        int v = 0;
        if (t < NBLK && t >= off) v = pref[t - off];
        __syncthreads();
        if (t < NBLK) pref[t] += v;
        __syncthreads();
    }
    int M = pref[NBLK - 1];

    for (int j = t; j < M; j += 1024) {
        int lo = 0, hi = NBLK - 1;
        while (lo < hi) { int mid = (lo + hi) >> 1; if (pref[mid] > j) hi = mid; else lo = mid + 1; }
        int within = j - (lo ? pref[lo - 1] : 0);
        unsigned wd = pairs[(size_t)lo * CHUNK + sstart[lo] + within];
        atomicAdd(&cur[wd & 511u], 1);
    }
    __syncthreads();

    int lane = t & 63, w = t >> 6;
    int myc = (t < 512) ? cur[t] : 0;
    int x = myc;
#pragma unroll
    for (int off = 1; off < 64; off <<= 1) {
        int u = __shfl_up(x, off);
        if (lane >= off) x += u;
    }
    if (lane == 63) wt2[w] = x;
    __syncthreads();
    int add = 0;
#pragma unroll
    for (int k = 0; k < 15; ++k) if (k < w) add += wt2[k];
    x += add;
    int gstart = bbase[b] + x - myc;
    if (t < 512) {
        if (nodeBase + t <= N_NODES) offs[nodeBase + t] = gstart;
        cur[t] = gstart;
    }
    __syncthreads();

    for (int j = t; j < M; j += 1024) {
        int lo = 0, hi = NBLK - 1;
        while (lo < hi) { int mid = (lo + hi) >> 1; if (pref[mid] > j) hi = mid; else lo = mid + 1; }
        int within = j - (lo ? pref[lo - 1] : 0);
        unsigned wd = pairs[(size_t)lo * CHUNK + sstart[lo] + within];
        int pos = atomicAdd(&cur[wd & 511u], 1);
        csr_src[pos] = (int)(wd >> 9);
    }
}

// ---------------- W -> bf16, fragment-ready layout (both weights) ----------------

__global__ __launch_bounds__(256) void wtconv_both(const float* __restrict__ W1, const float* __restrict__ W2,
                                                   unsigned short* __restrict__ Wt1, unsigned short* __restrict__ Wt2) {
    int i = blockIdx.x * 256 + threadIdx.x;
    const float* W = (i < F_IN * HC) ? W1 : W2;
    unsigned short* Wt = (i < F_IN * HC) ? Wt1 : Wt2;
    int j = (i < F_IN * HC) ? i : i - F_IN * HC;
    if (j < F_IN * HC) {
        int k = j >> 7, col = j & 127;
        Wt[(size_t)(k >> 3) * (HC * 8) + col * 8 + (k & 7)] = f2bf_rne(W[j]);
    }
}

// ---------------- aggregation: 8-lane edge groups, 16 fp8 ch/lane (full 128 B row/group) ---
// grp = lane>>3 (edge slot 0..7); q = lane&7 holds channels q*16..q*16+15; head = q>>2.
// 2x unroll -> 16 edges in flight/wave. Reduction: xor8/16/32 (preserves q). Lanes 0..7
// write 32 B each (channels q*16..+15).

__global__ __launch_bounds__(256) void agg_kernel(const int* __restrict__ offs, const int* __restrict__ csr_src,
                                                  const float* __restrict__ asrc, const float* __restrict__ adst,
                                                  const unsigned char* __restrict__ Hin,
                                                  const float* __restrict__ bias,
                                                  unsigned short* __restrict__ Hout, int do_relu) {
    int wid  = (blockIdx.x * 256 + threadIdx.x) >> 6;
    int lane = threadIdx.x & 63;
    if (wid >= N_NODES) return;
    int beg = offs[wid], end = offs[wid + 1];
    int grp = lane >> 3;           // edge slot 0..7
    int q   = lane & 7;            // channels q*16 .. q*16+15
    int head = q >> 2;
    float madst = adst[(size_t)wid * 2 + head];        // scalar load (own head)
    const unsigned char* hbase = Hin + q * 16;

    float den = 0.f;
    float ac[16];
#pragma unroll
    for (int i = 0; i < 16; ++i) ac[i] = 0.f;

    for (int e = beg + grp; e < end; e += 16) {
        int en = e + 8;
        bool v1 = en < end;
        int s0 = csr_src[e];
        int s1 = v1 ? csr_src[en] : s0;
        float aa0 = asrc[(size_t)s0 * 2 + head];       // scalar gathers (own head)
        float aa1 = asrc[(size_t)s1 * 2 + head];
        uint4 g0 = *(const uint4*)&hbase[(size_t)s0 * HC];
        uint4 g1 = *(const uint4*)&hbase[(size_t)s1 * HC];
        float l0 = aa0 + madst; l0 = l0 > 0.f ? l0 : NEG_SLOPE * l0;
        float l1 = aa1 + madst; l1 = l1 > 0.f ? l1 : NEG_SLOPE * l1;
        float w0 = __expf(l0);
        float w1 = v1 ? __expf(l1) : 0.f;
        den += w0 + w1;
        unsigned d0[4] = { g0.x, g0.y, g0.z, g0.w };
        unsigned d1[4] = { g1.x, g1.y, g1.z, g1.w };
#pragma unroll
        for (int k = 0; k < 4; ++k) {
            f32x2 p0a = __builtin_amdgcn_cvt_pk_f32_fp8(d0[k], 0);
            f32x2 p0b = __builtin_amdgcn_cvt_pk_f32_fp8(d0[k], 1);
            f32x2 p1a = __builtin_amdgcn_cvt_pk_f32_fp8(d1[k], 0);
            f32x2 p1b = __builtin_amdgcn_cvt_pk_f32_fp8(d1[k], 1);
            ac[k * 4 + 0] = fmaf(w1, p1a.x, fmaf(w0, p0a.x, ac[k * 4 + 0]));
            ac[k * 4 + 1] = fmaf(w1, p1a.y, fmaf(w0, p0a.y, ac[k * 4 + 1]));
            ac[k * 4 + 2] = fmaf(w1, p1b.x, fmaf(w0, p0b.x, ac[k * 4 + 2]));
            ac[k * 4 + 3] = fmaf(w1, p1b.y, fmaf(w0, p0b.y, ac[k * 4 + 3]));
        }
    }

#pragma unroll
    for (int off = 8; off <= 32; off <<= 1) {
        den += __shfl_xor(den, off);
#pragma unroll
        for (int i = 0; i < 16; ++i) ac[i] += __shfl_xor(ac[i], off);
    }

    if (lane < 8) {
        float inv = 1.0f / den;
        float o[16];
#pragma unroll
        for (int k = 0; k < 4; ++k) {
            float4 bb = *(const float4*)&bias[q * 16 + k * 4];
            o[k * 4 + 0] = fmaf(ac[k * 4 + 0], inv, bb.x);
            o[k * 4 + 1] = fmaf(ac[k * 4 + 1], inv, bb.y);
            o[k * 4 + 2] = fmaf(ac[k * 4 + 2], inv, bb.z);
            o[k * 4 + 3] = fmaf(ac[k * 4 + 3], inv, bb.w);
        }
        if (do_relu) {
#pragma unroll
            for (int i = 0; i < 16; ++i) o[i] = fmaxf(o[i], 0.f);
        }
        uint4 st0, st1;
        st0.x = (unsigned)f2bf_rne(o[0])  | ((unsigned)f2bf_rne(o[1])  << 16);
        st0.y = (unsigned)f2bf_rne(o[2])  | ((unsigned)f2bf_rne(o[3])  << 16);
        st0.z = (unsigned)f2bf_rne(o[4])  | ((unsigned)f2bf_rne(o[5])  << 16);
        st0.w = (unsigned)f2bf_rne(o[6])  | ((unsigned)f2bf_rne(o[7])  << 16);
        st1.x = (unsigned)f2bf_rne(o[8])  | ((unsigned)f2bf_rne(o[9])  << 16);
        st1.y = (unsigned)f2bf_rne(o[10]) | ((unsigned)f2bf_rne(o[11]) << 16);
        st1.z = (unsigned)f2bf_rne(o[12]) | ((unsigned)f2bf_rne(o[13]) << 16);
        st1.w = (unsigned)f2bf_rne(o[14]) | ((unsigned)f2bf_rne(o[15]) << 16);
        *(uint4*)&Hout[(size_t)wid * HC + q * 16]     = st0;
        *(uint4*)&Hout[(size_t)wid * HC + q * 16 + 8] = st1;
    }
}

// ---------------- mean pool (bf16 input; 8K atomics only) ----------------

__global__ __launch_bounds__(256) void pool_kernel(const unsigned short* __restrict__ H2,
                                                   const int* __restrict__ counts,
                                                   float* __restrict__ out) {
    int g = blockIdx.x;
    int chunk = blockIdx.y;
    __shared__ int soff, scnt;
    if (threadIdx.x == 0) {
        int s = 0;
        for (int i = 0; i < g; ++i) s += counts[i];
        soff = s; scnt = counts[g];
    }
    __syncthreads();
    int start = soff, cnt = scnt;
    int r = threadIdx.x >> 7;
    int c = threadIdx.x & 127;
    float acc = 0.f;
    for (int v = chunk * 2 + r; v < cnt; v += 16)
        acc += bf2f((unsigned)H2[(size_t)(start + v) * HC + c]);
    float inv = 1.0f / fmaxf((float)cnt, 1.0f);
    atomicAdd(&out[g * HC + c], acc * inv);
}

// ---------------- launch ----------------

extern "C" void kernel_launch(void* const* d_in, const int* in_sizes, int n_in,
                              void* d_out, int out_size, void* d_ws, size_t ws_size,
                              hipStream_t stream) {
    const float* x     = (const float*)d_in[0];
    const int*   ei    = (const int*)d_in[1];
    const int*   batch = (const int*)d_in[2];
    const float* W1    = (const float*)d_in[3];
    const float* a1s   = (const float*)d_in[4];
    const float* a1d   = (const float*)d_in[5];
    const float* b1    = (const float*)d_in[6];
    const float* W2    = (const float*)d_in[7];
    const float* a2s   = (const float*)d_in[8];
    const float* a2d   = (const float*)d_in[9];
    const float* b2    = (const float*)d_in[10];
    float* out = (float*)d_out;

    char* ws = (char*)d_ws;
    const size_t NH = (size_t)N_NODES * HC;
    unsigned char* hA = (unsigned char*)ws;                 // fp8 gather table, 12.8 MB
    unsigned short* hB = (unsigned short*)(ws + NH);        // bf16, 25.6 MB
    unsigned* pairs = (unsigned*)(hB + NH);                 // 6.8 MB
    float* asrc = (float*)(pairs + (size_t)NBLK * CHUNK);
    float* adst = asrc + (size_t)N_NODES * 2;
    unsigned short* wt1 = (unsigned short*)(adst + (size_t)N_NODES * 2);
    unsigned short* wt2 = wt1 + F_IN * HC;
    int*   offs = (int*)(wt2 + F_IN * HC);
    int*   csr  = offs + (N_NODES + 1);
    int*   seg_start = csr + TOT_E;
    int*   seg_cnt   = seg_start + (size_t)NBLK * NBUCK;
    int*   btot = seg_cnt + (size_t)NBLK * NBUCK;
    int*   bbase = btot + NBUCK;
    int*   counts = bbase + NBUCK;

    hipMemsetAsync(counts, 0, NGRAPH * sizeof(int), stream);
    hipMemsetAsync(out, 0, (size_t)out_size * sizeof(float), stream);

    // weights -> bf16 fragment layout (both layers, one launch)
    wtconv_both<<<(2 * F_IN * HC + 255) / 256, 256, 0, stream>>>(W1, W2, wt1, wt2);

    // fused: gemm1(+alpha) ⊗ binpart ⊗ counts
    fused_main<<<GEMM_B + NBLK + CNT_B, 256, 0, stream>>>(x, wt1, hA, a1s, a1d, asrc, adst,
                                                          ei, pairs, seg_start, seg_cnt,
                                                          batch, counts);

    // CSR finalize
    btot_kernel<<<NBUCK, 256, 0, stream>>>(seg_cnt, btot);
    bbase_kernel<<<1, 256, 0, stream>>>(btot, bbase);
    bucket_build<<<NBUCK, 1024, 0, stream>>>(pairs, seg_start, seg_cnt, bbase, offs, csr);

    int waveBlocks = (N_NODES + 3) / 4;

    // layer 1 aggregation
    agg_kernel<<<waveBlocks, 256, 0, stream>>>(offs, csr, asrc, adst, hA, b1, hB, 1);

    // layer 2
    gemm2_kernel<<<GEMM_B, 256, 0, stream>>>(hB, wt2, hA, a2s, a2d, asrc, adst);
    agg_kernel<<<waveBlocks, 256, 0, stream>>>(offs, csr, asrc, adst, hA, b2, hB, 0);

    // pool
    pool_kernel<<<dim3(NGRAPH, 8), 256, 0, stream>>>(hB, counts, out);
}